// Round 13
// baseline (327.518 us; speedup 1.0000x reference)
//
#include <hip/hip_runtime.h>
#include <cstdint>
#include <cstddef>

typedef __bf16 bf16_t;
typedef __bf16 bf16x8 __attribute__((ext_vector_type(8)));
typedef float f32x4  __attribute__((ext_vector_type(4)));
typedef float f32x16 __attribute__((ext_vector_type(16)));
typedef int   i32x4  __attribute__((ext_vector_type(4)));

#define DEVI static __device__ __forceinline__

DEVI f32x4 mfma16(bf16x8 a, bf16x8 b, f32x4 c) {
  return __builtin_amdgcn_mfma_f32_16x16x32_bf16(a, b, c, 0, 0, 0);
}
DEVI f32x16 mfma32(bf16x8 a, bf16x8 b, f32x16 c) {
  return __builtin_amdgcn_mfma_f32_32x32x16_bf16(a, b, c, 0, 0, 0);
}
DEVI unsigned cvtpk(float lo, float hi) {
  unsigned d;
  asm("v_cvt_pk_bf16_f32 %0, %1, %2" : "=v"(d) : "v"(lo), "v"(hi));
  return d;
}
DEVI void gload_lds16(const bf16_t* g, bf16_t* l) {
  __builtin_amdgcn_global_load_lds(
      (const __attribute__((address_space(1))) void*)g,
      (__attribute__((address_space(3))) void*)l, 16, 0, 0);
}

#define L2E 1.44269504f
#define QSCALE (0.125f * L2E)      // folded into Q projection output

// ---------------------------------------------------------------------------
// Fused converters (memory-bound; 8 f32 -> 8 bf16 / thread)
// ---------------------------------------------------------------------------
__global__ __launch_bounds__(256)
void cvt_qkv(const float* __restrict__ a0, const float* __restrict__ a1,
             const float* __restrict__ a2, bf16_t* __restrict__ o0,
             bf16_t* __restrict__ o1, bf16_t* __restrict__ o2, int n8)
{
  const int i = blockIdx.x * 256 + threadIdx.x;
  if (i >= n8) return;
  const float* in; bf16_t* out;
  if (blockIdx.y == 0)      { in = a0; out = o0; }
  else if (blockIdx.y == 1) { in = a1; out = o1; }
  else                      { in = a2; out = o2; }
  float4 a = ((const float4*)in)[2*i];
  float4 b = ((const float4*)in)[2*i + 1];
  bf16x8 o;
  o[0]=(bf16_t)a.x; o[1]=(bf16_t)a.y; o[2]=(bf16_t)a.z; o[3]=(bf16_t)a.w;
  o[4]=(bf16_t)b.x; o[5]=(bf16_t)b.y; o[6]=(bf16_t)b.z; o[7]=(bf16_t)b.w;
  ((bf16x8*)out)[i] = o;
}

__global__ __launch_bounds__(256)
void cvt_w(const float* __restrict__ wq, const float* __restrict__ wk,
           const float* __restrict__ wv, const float* __restrict__ wo,
           const int* __restrict__ mask,
           bf16_t* __restrict__ oq, bf16_t* __restrict__ ok,
           bf16_t* __restrict__ ov, bf16_t* __restrict__ ooh,
           bf16_t* __restrict__ ool, bf16_t* __restrict__ maskbit, int n8)
{
  const int i = blockIdx.x * 256 + threadIdx.x;
  const int y = blockIdx.y;
  if (y < 3) {
    if (i >= n8) return;
    const float* in = (y == 0) ? wq : (y == 1) ? wk : wv;
    bf16_t* out     = (y == 0) ? oq : (y == 1) ? ok : ov;
    float4 a = ((const float4*)in)[2*i];
    float4 b = ((const float4*)in)[2*i + 1];
    bf16x8 o;
    o[0]=(bf16_t)a.x; o[1]=(bf16_t)a.y; o[2]=(bf16_t)a.z; o[3]=(bf16_t)a.w;
    o[4]=(bf16_t)b.x; o[5]=(bf16_t)b.y; o[6]=(bf16_t)b.z; o[7]=(bf16_t)b.w;
    ((bf16x8*)out)[i] = o;
  } else if (y == 3) {
    if (i >= n8) return;
    float4 a = ((const float4*)wo)[2*i];
    float4 b = ((const float4*)wo)[2*i + 1];
    const float* f = (const float*)&a;
    bf16x8 oh, ol;
    #pragma unroll
    for (int j = 0; j < 4; ++j) { bf16_t h=(bf16_t)f[j]; oh[j]=h; ol[j]=(bf16_t)(f[j]-(float)h); }
    const float* f2 = (const float*)&b;
    #pragma unroll
    for (int j = 0; j < 4; ++j) { bf16_t h=(bf16_t)f2[j]; oh[4+j]=h; ol[4+j]=(bf16_t)(f2[j]-(float)h); }
    ((bf16x8*)ooh)[i] = oh;
    ((bf16x8*)ool)[i] = ol;
  } else {
    // maskbit: 4*2048 ints -> bf16 1.0/0.0
    if (i >= 1024) return;
    i32x4 m0 = ((const i32x4*)mask)[2*i];
    i32x4 m1 = ((const i32x4*)mask)[2*i + 1];
    bf16x8 o;
    #pragma unroll
    for (int j = 0; j < 4; ++j) o[j]     = m0[j] ? (bf16_t)1.0f : (bf16_t)0.0f;
    #pragma unroll
    for (int j = 0; j < 4; ++j) o[4 + j] = m1[j] ? (bf16_t)1.0f : (bf16_t)0.0f;
    ((bf16x8*)maskbit)[i] = o;
  }
}

// ---------------------------------------------------------------------------
// proj_gemm97: C = (A[8192,1024](bf16) @ W^T(bf16) + bias) * oscale, out bf16.
// 128x64 tile (BN=64 -> grid 16x64 = 1024 blocks = 4/CU, 2x the occupancy of
// the 128x128 version whose 512-block grid capped at 2/CU). BK=64,
// global_load_lds width=16, linear LDS, 2 barriers/K-step, 4 waves.
// Wave w owns rows w*32..w*32+31 x all 64 cols.
// OMODE 1: out[b,h,s,d];  OMODE 2: out[b,h,d,s] transposed V, masked rows 0.
// ---------------------------------------------------------------------------
template<int OMODE>
__global__ __launch_bounds__(256)
void proj_gemm97(const bf16_t* __restrict__ A, const bf16_t* __restrict__ W,
                 const float* __restrict__ bias, bf16_t* __restrict__ Out,
                 float oscale, const int* __restrict__ mask)
{
  __shared__ __align__(16) bf16_t As[128 * 64];   // 16 KB
  __shared__ __align__(16) bf16_t Bs[64 * 64];    //  8 KB
  const int tid  = threadIdx.x;
  const int lane = tid & 63;
  const int w    = tid >> 6;
  const int g = lane >> 4, c = lane & 15;
  const int bm = blockIdx.y, bn = blockIdx.x;

  const int rsub = lane >> 3;
  const int kc8  = (lane & 7) * 8;

  f32x4 acc[2][4] = {};

  for (int kt = 0; kt < 1024; kt += 64) {
    #pragma unroll
    for (int i = 0; i < 4; ++i) {          // A: 16 inst-groups cover 128 rows
      const int inst = w * 4 + i;
      const int row  = inst * 8 + rsub;
      gload_lds16(A + (size_t)(bm*128 + row)*1024 + kt + kc8, &As[inst*512]);
    }
    #pragma unroll
    for (int j = 0; j < 2; ++j) {          // B: 8 inst-groups cover 64 rows
      const int binst = w * 2 + j;
      const int row   = binst * 8 + rsub;
      gload_lds16(W + (size_t)(bn*64 + row)*1024 + kt + kc8, &Bs[binst*512]);
    }
    __syncthreads();
    #pragma unroll
    for (int kk = 0; kk < 64; kk += 32) {
      bf16x8 af[2], bfv[4];
      #pragma unroll
      for (int i = 0; i < 2; ++i)
        af[i]  = *(const bf16x8*)&As[(w*32 + i*16 + c)*64 + kk + 8*g];
      #pragma unroll
      for (int i = 0; i < 4; ++i)
        bfv[i] = *(const bf16x8*)&Bs[(i*16 + c)*64 + kk + 8*g];
      #pragma unroll
      for (int mi = 0; mi < 2; ++mi)
        #pragma unroll
        for (int ni = 0; ni < 4; ++ni)
          acc[mi][ni] = mfma16(af[mi], bfv[ni], acc[mi][ni]);
    }
    __syncthreads();
  }

  #pragma unroll
  for (int ni = 0; ni < 4; ++ni) {
    const int n = bn*64 + ni*16 + c;
    const float bv = bias[n];
    const int h = n >> 6, d = n & 63;
    #pragma unroll
    for (int mi = 0; mi < 2; ++mi) {
      #pragma unroll
      for (int r = 0; r < 4; ++r) {
        const int m = bm*128 + w*32 + mi*16 + 4*g + r;
        const int bb = m >> 11, s = m & 2047;
        float v = (acc[mi][ni][r] + bv) * oscale;
        if (OMODE == 1) {
          Out[(((size_t)(bb*16 + h))*2048 + s)*64 + d] = (bf16_t)v;
        } else {
          if (mask[bb*2048 + s] == 0) v = 0.0f;   // fold key-mask into V rows
          Out[(((size_t)(bb*16 + h))*64 + d)*2048 + s] = (bf16_t)v;
        }
      }
    }
  }
}

// ---------------------------------------------------------------------------
// out_gemm97: split-precision GEMM from pure-bf16 inputs:
//   Out = Ah Bh + Al Bh + Ah Bl + bias   (f32-class accuracy)
// 128x64 tile -> grid 16x64 = 1024 blocks (was 512 = 2/CU grid-capped);
// LDS 48 KB -> 3 blocks/CU resident.
// ---------------------------------------------------------------------------
__global__ __launch_bounds__(256)
void out_gemm97(const bf16_t* __restrict__ Ahg, const bf16_t* __restrict__ Alg,
                const bf16_t* __restrict__ Bhg, const bf16_t* __restrict__ Blg,
                const float* __restrict__ bias, float* __restrict__ Out)
{
  __shared__ __align__(16) bf16_t Ahs[128 * 64];  // 16 KB
  __shared__ __align__(16) bf16_t Als[128 * 64];  // 16 KB
  __shared__ __align__(16) bf16_t Bhs[64 * 64];   //  8 KB
  __shared__ __align__(16) bf16_t Bls[64 * 64];   //  8 KB
  const int tid  = threadIdx.x;
  const int lane = tid & 63;
  const int w    = tid >> 6;
  const int g = lane >> 4, c = lane & 15;
  const int bm = blockIdx.y, bn = blockIdx.x;

  const int rsub = lane >> 3;
  const int kc8  = (lane & 7) * 8;

  f32x4 acc[2][4] = {};

  for (int kt = 0; kt < 1024; kt += 64) {
    #pragma unroll
    for (int i = 0; i < 4; ++i) {
      const int inst = w * 4 + i;
      const int row  = inst * 8 + rsub;
      const size_t ga = (size_t)(bm*128 + row)*1024 + kt + kc8;
      gload_lds16(Ahg + ga, &Ahs[inst*512]);
      gload_lds16(Alg + ga, &Als[inst*512]);
    }
    #pragma unroll
    for (int j = 0; j < 2; ++j) {
      const int binst = w * 2 + j;
      const int row   = binst * 8 + rsub;
      const size_t gb = (size_t)(bn*64 + row)*1024 + kt + kc8;
      gload_lds16(Bhg + gb, &Bhs[binst*512]);
      gload_lds16(Blg + gb, &Bls[binst*512]);
    }
    __syncthreads();
    #pragma unroll
    for (int kk = 0; kk < 64; kk += 32) {
      bf16x8 afh[2], afl[2], bfh[4], bfl[4];
      #pragma unroll
      for (int i = 0; i < 2; ++i) {
        const int ar = (w*32 + i*16 + c)*64 + kk + 8*g;
        afh[i] = *(const bf16x8*)&Ahs[ar];
        afl[i] = *(const bf16x8*)&Als[ar];
      }
      #pragma unroll
      for (int i = 0; i < 4; ++i) {
        const int br = (i*16 + c)*64 + kk + 8*g;
        bfh[i] = *(const bf16x8*)&Bhs[br];
        bfl[i] = *(const bf16x8*)&Bls[br];
      }
      #pragma unroll
      for (int mi = 0; mi < 2; ++mi)
        #pragma unroll
        for (int ni = 0; ni < 4; ++ni) {
          acc[mi][ni] = mfma16(afh[mi], bfh[ni], acc[mi][ni]);
          acc[mi][ni] = mfma16(afl[mi], bfh[ni], acc[mi][ni]);
          acc[mi][ni] = mfma16(afh[mi], bfl[ni], acc[mi][ni]);
        }
    }
    __syncthreads();
  }

  #pragma unroll
  for (int ni = 0; ni < 4; ++ni) {
    const int n = bn*64 + ni*16 + c;
    const float bv = bias[n];
    #pragma unroll
    for (int mi = 0; mi < 2; ++mi)
      #pragma unroll
      for (int r = 0; r < 4; ++r) {
        const int m = bm*128 + w*32 + mi*16 + 4*g + r;
        Out[(size_t)m*1024 + n] = acc[mi][ni][r] + bv;
      }
  }
}

// ---------------------------------------------------------------------------
// Flash attention: swapped-QK^T 32x32 MFMA, in-register softmax.
// (unchanged from the verified 132 us round-12 state)
// ---------------------------------------------------------------------------
__global__ __launch_bounds__(256, 3)
void attn_kernel(const bf16_t* __restrict__ Q, const bf16_t* __restrict__ K,
                 const bf16_t* __restrict__ Vt, const bf16_t* __restrict__ maskbit,
                 const float* __restrict__ rel_emb,
                 bf16_t* __restrict__ Ch, bf16_t* __restrict__ Cl)
{
  __shared__ float relc[257];                      // rel_emb[.,h] * log2e
  __shared__ __align__(16) bf16_t Ks[2][64][72];   // [buf][s'][d]
  __shared__ __align__(16) bf16_t Vs[2][64][72];   // [buf][d][s']

  const int tid  = threadIdx.x;
  const int w    = tid >> 6;
  const int lane = tid & 63;
  const int lq   = lane & 31;
  const int hi   = lane >> 5;

  const int bid = blockIdx.x;
  const int n   = (bid & 7) * 128 + (bid >> 3);   // XCD-chunked (1024 % 8 == 0)
  const int bh  = n >> 4;
  const int qblk= n & 15;
  const int b = bh >> 4, h = bh & 15;
  const int qw = qblk * 128 + w * 32;             // wave's q-base

  const bf16_t* Qb = Q  + ((size_t)bh * 2048) * 64;
  const bf16_t* Kb = K  + ((size_t)bh * 2048) * 64;
  const bf16_t* Vb = Vt + ((size_t)bh * 64) * 2048;
  const bf16_t* Mb = maskbit + (size_t)b * 2048;

  const int sr  = tid >> 2;            // staging row 0..63
  const int so  = (tid & 3) * 16;      // staging col

  for (int i = tid; i < 257; i += 256) relc[i] = rel_emb[i * 16 + h] * L2E;

  // ---- prologue: stage tile 0 into buf 0 ----
  {
    const bf16_t* kp = Kb + (size_t)sr * 64 + so;
    const bf16_t* vp = Vb + (size_t)sr * 2048 + so;
    i32x4 k0 = *(const i32x4*)kp, k1 = *(const i32x4*)(kp + 8);
    i32x4 v0 = *(const i32x4*)vp, v1 = *(const i32x4*)(vp + 8);
    *(i32x4*)&Ks[0][sr][so] = k0;  *(i32x4*)&Ks[0][sr][so + 8] = k1;
    *(i32x4*)&Vs[0][sr][so] = v0;  *(i32x4*)&Vs[0][sr][so + 8] = v1;
  }
  __syncthreads();

  bf16x8 qf[4];
  #pragma unroll
  for (int dc = 0; dc < 4; ++dc)
    qf[dc] = *(const bf16x8*)&Qb[(size_t)(qw + lq) * 64 + dc * 16 + 8 * hi];

  const float biasLo = relc[0];
  const float biasHi = relc[256];

  f32x16 O0 = {}, O1 = {}, Ol = {};

  // fused softmax+pack: sa (C[k][q]) -> two PV A-frags
  auto SMPK = [&](const f32x16& sa, int kvc, bf16x8& pa0, bf16x8& pa1) {
    unsigned u[8];
    const int d0 = kvc - qw;
    if (d0 >= 160 || d0 <= -160) {
      const float cb = (d0 >= 160) ? biasHi : biasLo;
      #pragma unroll
      for (int j = 0; j < 8; ++j)
        u[j] = cvtpk(exp2f(sa[2*j] + cb), exp2f(sa[2*j + 1] + cb));
    } else {
      #pragma unroll
      for (int j = 0; j < 8; ++j) {
        const int r0 = 2*j, r1 = 2*j + 1;
        const int k0r = (r0 & 3) + 8 * (r0 >> 2) + 4 * hi;
        const int k1r = (r1 & 3) + 8 * (r1 >> 2) + 4 * hi;
        int rr0 = kvc + k0r - (qw + lq);
        int rr1 = kvc + k1r - (qw + lq);
        rr0 = rr0 < -128 ? -128 : (rr0 > 128 ? 128 : rr0);
        rr1 = rr1 < -128 ? -128 : (rr1 > 128 ? 128 : rr1);
        u[j] = cvtpk(exp2f(sa[r0] + relc[rr0 + 128]),
                     exp2f(sa[r1] + relc[rr1 + 128]));
      }
    }
    asm volatile("v_permlane32_swap_b32 %0, %1" : "+v"(u[0]), "+v"(u[2]));
    asm volatile("v_permlane32_swap_b32 %0, %1" : "+v"(u[1]), "+v"(u[3]));
    i32x4 pw0 = { (int)u[0], (int)u[1], (int)u[2], (int)u[3] };
    pa0 = __builtin_bit_cast(bf16x8, pw0);
    asm volatile("v_permlane32_swap_b32 %0, %1" : "+v"(u[4]), "+v"(u[6]));
    asm volatile("v_permlane32_swap_b32 %0, %1" : "+v"(u[5]), "+v"(u[7]));
    i32x4 pw1 = { (int)u[4], (int)u[5], (int)u[6], (int)u[7] };
    pa1 = __builtin_bit_cast(bf16x8, pw1);
  };

  // one 32-row chunk end-to-end: QK^T -> (mb loads) -> exp/pack -> PV
  auto CHUNK = [&](int cur, int koff, int kvc) {
    bf16x8 kf[4];
    #pragma unroll
    for (int dc = 0; dc < 4; ++dc)
      kf[dc] = *(const bf16x8*)&Ks[cur][koff + lq][dc * 16 + 8 * hi];
    f32x16 sa = {};
    __builtin_amdgcn_s_setprio(1);
    #pragma unroll
    for (int dc = 0; dc < 4; ++dc) sa = mfma32(kf[dc], qf[dc], sa);
    __builtin_amdgcn_s_setprio(0);

    // mb loads BEFORE exp/pack: L2 latency hides under SMPK's VALU
    bf16x8 mba = *(const bf16x8*)&Mb[kvc + 8 * hi];
    bf16x8 mbb = *(const bf16x8*)&Mb[kvc + 16 + 8 * hi];

    bf16x8 pa0, pa1;
    SMPK(sa, kvc, pa0, pa1);

    const int c0 = koff;                 // 0 or 32 -> V col pairs 0/16, 32/48
    bf16x8 vf00 = *(const bf16x8*)&Vs[cur][lq]     [c0 + 8 * hi];
    bf16x8 vf01 = *(const bf16x8*)&Vs[cur][32 + lq][c0 + 8 * hi];
    bf16x8 vf10 = *(const bf16x8*)&Vs[cur][lq]     [c0 + 16 + 8 * hi];
    bf16x8 vf11 = *(const bf16x8*)&Vs[cur][32 + lq][c0 + 16 + 8 * hi];

    __builtin_amdgcn_s_setprio(1);
    O0 = mfma32(pa0, vf00, O0);
    O1 = mfma32(pa0, vf01, O1);
    Ol = mfma32(pa0, mba,  Ol);
    O0 = mfma32(pa1, vf10, O0);
    O1 = mfma32(pa1, vf11, O1);
    Ol = mfma32(pa1, mbb,  Ol);
    __builtin_amdgcn_s_setprio(0);
  };

  for (int t = 0; t < 32; ++t) {
    const int kv  = t * 64;
    const int cur = t & 1, nxt = cur ^ 1;
    const bool more = (t + 1 < 32);

    // ---- issue stage loads for tile t+1 ----
    i32x4 k0, k1, v0, v1;
    if (more) {
      const bf16_t* kp = Kb + (size_t)(kv + 64 + sr) * 64 + so;
      const bf16_t* vp = Vb + (size_t)sr * 2048 + (kv + 64) + so;
      k0 = *(const i32x4*)kp;  k1 = *(const i32x4*)(kp + 8);
      v0 = *(const i32x4*)vp;  v1 = *(const i32x4*)(vp + 8);
    }

    // ---- chunk 0 end-to-end (hides stage-load latency) ----
    CHUNK(cur, 0, kv);

    // ---- mid-iteration stage write: nxt buffer was last read in iter t-1
    //      (barrier passed); frees staging regs before chunk 1 ----
    if (more) {
      *(i32x4*)&Ks[nxt][sr][so] = k0;  *(i32x4*)&Ks[nxt][sr][so + 8] = k1;
      *(i32x4*)&Vs[nxt][sr][so] = v0;  *(i32x4*)&Vs[nxt][sr][so + 8] = v1;
    }

    // ---- chunk 1 end-to-end ----
    CHUNK(cur, 32, kv + 32);

    __syncthreads();
  }

  // ---- epilogue: each lane's Ol[reg] is its q-row's full denominator ----
  #pragma unroll
  for (int reg = 0; reg < 16; ++reg) {
    const int qrow = (reg & 3) + 8 * (reg >> 2) + 4 * hi;
    const float sum = Ol[reg];
    const float iv = (sum > 0.0f) ? 1.0f / sum : 0.0f;  // all-masked row -> 0
    const int s = qw + qrow;
    const size_t base = ((size_t)(b * 2048 + s)) * 1024 + h * 64 + lq;
    const float o0 = O0[reg] * iv, o1 = O1[reg] * iv;
    const bf16_t h0 = (bf16_t)o0, h1 = (bf16_t)o1;
    Ch[base]      = h0;  Cl[base]      = (bf16_t)(o0 - (float)h0);
    Ch[base + 32] = h1;  Cl[base + 32] = (bf16_t)(o1 - (float)h1);
  }
}

// ---------------------------------------------------------------------------
extern "C" void kernel_launch(void* const* d_in, const int* in_sizes, int n_in,
                              void* d_out, int out_size, void* d_ws, size_t ws_size,
                              hipStream_t stream)
{
  const float* q    = (const float*)d_in[0];
  const float* k    = (const float*)d_in[1];
  const float* v    = (const float*)d_in[2];
  const int*   mask = (const int*)  d_in[3];
  const float* Wq   = (const float*)d_in[4];
  const float* bq   = (const float*)d_in[5];
  const float* Wk   = (const float*)d_in[6];
  const float* bk   = (const float*)d_in[7];
  const float* Wv   = (const float*)d_in[8];
  const float* bv   = (const float*)d_in[9];
  const float* Wo   = (const float*)d_in[10];
  const float* bo   = (const float*)d_in[11];
  const float* rel  = (const float*)d_in[12];

  char* wsb = (char*)d_ws;
  bf16_t* Qw  = (bf16_t*)(wsb);                         // 16 MiB proj-Q out
  bf16_t* Kw  = (bf16_t*)(wsb + ((size_t) 16 << 20));   // 16 MiB proj-K out
  bf16_t* Vw  = (bf16_t*)(wsb + ((size_t) 32 << 20));   // 16 MiB proj-V out (T, masked)
  bf16_t* Qc  = (bf16_t*)(wsb + ((size_t) 48 << 20));   // query bf16 / later Ch
  bf16_t* Kc  = (bf16_t*)(wsb + ((size_t) 64 << 20));   // key   bf16 / later Cl
  bf16_t* Vc  = (bf16_t*)(wsb + ((size_t) 80 << 20));   // value bf16
  bf16_t* Wqc = (bf16_t*)(wsb + ((size_t) 96 << 20));   // 2 MiB each
  bf16_t* Wkc = (bf16_t*)(wsb + ((size_t) 98 << 20));
  bf16_t* Wvc = (bf16_t*)(wsb + ((size_t)100 << 20));
  bf16_t* Woh = (bf16_t*)(wsb + ((size_t)102 << 20));
  bf16_t* Wol = (bf16_t*)(wsb + ((size_t)104 << 20));
  bf16_t* Mbit= (bf16_t*)(wsb + ((size_t)106 << 20));   // 16 KiB maskbit bf16
  bf16_t* Chp = Qc;   // ctx split-high, aliases consumed Qc
  bf16_t* Clp = Kc;   // ctx split-low,  aliases consumed Kc

  const int n8t = 8192 * 1024 / 8;
  const int n8w = 1024 * 1024 / 8;
  dim3 bb(256);

  cvt_qkv<<<dim3(4096, 3), bb, 0, stream>>>(q, k, v, Qc, Kc, Vc, n8t);
  cvt_w<<<dim3(512, 5), bb, 0, stream>>>(Wq, Wk, Wv, Wo, mask,
                                         Wqc, Wkc, Wvc, Woh, Wol, Mbit, n8w);

  proj_gemm97<1><<<dim3(16, 64), bb, 0, stream>>>(Qc, Wqc, bq, Qw, QSCALE, mask);
  proj_gemm97<1><<<dim3(16, 64), bb, 0, stream>>>(Kc, Wkc, bk, Kw, 1.0f, mask);
  proj_gemm97<2><<<dim3(16, 64), bb, 0, stream>>>(Vc, Wvc, bv, Vw, 1.0f, mask);
  attn_kernel<<<dim3(1024), bb, 0, stream>>>(Qw, Kw, Vw, Mbit, rel, Chp, Clp);
  out_gemm97<<<dim3(16, 64), bb, 0, stream>>>(Chp, Clp, Woh, Wol, bo, (float*)d_out);
}

// Round 14
// 282.817 us; speedup vs baseline: 1.1581x; 1.1581x over previous
//
#include <hip/hip_runtime.h>
#include <cstdint>
#include <cstddef>

typedef __bf16 bf16_t;
typedef __bf16 bf16x8 __attribute__((ext_vector_type(8)));
typedef float f32x4  __attribute__((ext_vector_type(4)));
typedef float f32x16 __attribute__((ext_vector_type(16)));
typedef int   i32x4  __attribute__((ext_vector_type(4)));

#define DEVI static __device__ __forceinline__

DEVI f32x4 mfma16(bf16x8 a, bf16x8 b, f32x4 c) {
  return __builtin_amdgcn_mfma_f32_16x16x32_bf16(a, b, c, 0, 0, 0);
}
DEVI f32x16 mfma32(bf16x8 a, bf16x8 b, f32x16 c) {
  return __builtin_amdgcn_mfma_f32_32x32x16_bf16(a, b, c, 0, 0, 0);
}
DEVI unsigned cvtpk(float lo, float hi) {
  unsigned d;
  asm("v_cvt_pk_bf16_f32 %0, %1, %2" : "=v"(d) : "v"(lo), "v"(hi));
  return d;
}
DEVI void gload_lds16(const bf16_t* g, bf16_t* l) {
  __builtin_amdgcn_global_load_lds(
      (const __attribute__((address_space(1))) void*)g,
      (__attribute__((address_space(3))) void*)l, 16, 0, 0);
}

#define L2E 1.44269504f
#define QSCALE (0.125f * L2E)      // folded into Q projection output

// ---------------------------------------------------------------------------
// Fused converters (memory-bound; 8 f32 -> 8 bf16 / thread)
// ---------------------------------------------------------------------------
__global__ __launch_bounds__(256)
void cvt_qkv(const float* __restrict__ a0, const float* __restrict__ a1,
             const float* __restrict__ a2, bf16_t* __restrict__ o0,
             bf16_t* __restrict__ o1, bf16_t* __restrict__ o2, int n8)
{
  const int i = blockIdx.x * 256 + threadIdx.x;
  if (i >= n8) return;
  const float* in; bf16_t* out;
  if (blockIdx.y == 0)      { in = a0; out = o0; }
  else if (blockIdx.y == 1) { in = a1; out = o1; }
  else                      { in = a2; out = o2; }
  float4 a = ((const float4*)in)[2*i];
  float4 b = ((const float4*)in)[2*i + 1];
  bf16x8 o;
  o[0]=(bf16_t)a.x; o[1]=(bf16_t)a.y; o[2]=(bf16_t)a.z; o[3]=(bf16_t)a.w;
  o[4]=(bf16_t)b.x; o[5]=(bf16_t)b.y; o[6]=(bf16_t)b.z; o[7]=(bf16_t)b.w;
  ((bf16x8*)out)[i] = o;
}

__global__ __launch_bounds__(256)
void cvt_w(const float* __restrict__ wq, const float* __restrict__ wk,
           const float* __restrict__ wv, const float* __restrict__ wo,
           const int* __restrict__ mask,
           bf16_t* __restrict__ oq, bf16_t* __restrict__ ok,
           bf16_t* __restrict__ ov, bf16_t* __restrict__ ooh,
           bf16_t* __restrict__ ool, bf16_t* __restrict__ maskbit, int n8)
{
  const int i = blockIdx.x * 256 + threadIdx.x;
  const int y = blockIdx.y;
  if (y < 3) {
    if (i >= n8) return;
    const float* in = (y == 0) ? wq : (y == 1) ? wk : wv;
    bf16_t* out     = (y == 0) ? oq : (y == 1) ? ok : ov;
    float4 a = ((const float4*)in)[2*i];
    float4 b = ((const float4*)in)[2*i + 1];
    bf16x8 o;
    o[0]=(bf16_t)a.x; o[1]=(bf16_t)a.y; o[2]=(bf16_t)a.z; o[3]=(bf16_t)a.w;
    o[4]=(bf16_t)b.x; o[5]=(bf16_t)b.y; o[6]=(bf16_t)b.z; o[7]=(bf16_t)b.w;
    ((bf16x8*)out)[i] = o;
  } else if (y == 3) {
    if (i >= n8) return;
    float4 a = ((const float4*)wo)[2*i];
    float4 b = ((const float4*)wo)[2*i + 1];
    const float* f = (const float*)&a;
    bf16x8 oh, ol;
    #pragma unroll
    for (int j = 0; j < 4; ++j) { bf16_t h=(bf16_t)f[j]; oh[j]=h; ol[j]=(bf16_t)(f[j]-(float)h); }
    const float* f2 = (const float*)&b;
    #pragma unroll
    for (int j = 0; j < 4; ++j) { bf16_t h=(bf16_t)f2[j]; oh[4+j]=h; ol[4+j]=(bf16_t)(f2[j]-(float)h); }
    ((bf16x8*)ooh)[i] = oh;
    ((bf16x8*)ool)[i] = ol;
  } else {
    // maskbit: 4*2048 ints -> bf16 1.0/0.0
    if (i >= 1024) return;
    i32x4 m0 = ((const i32x4*)mask)[2*i];
    i32x4 m1 = ((const i32x4*)mask)[2*i + 1];
    bf16x8 o;
    #pragma unroll
    for (int j = 0; j < 4; ++j) o[j]     = m0[j] ? (bf16_t)1.0f : (bf16_t)0.0f;
    #pragma unroll
    for (int j = 0; j < 4; ++j) o[4 + j] = m1[j] ? (bf16_t)1.0f : (bf16_t)0.0f;
    ((bf16x8*)maskbit)[i] = o;
  }
}

// ---------------------------------------------------------------------------
// proj_gemm97: C = (A[8192,1024](bf16) @ W^T(bf16) + bias) * oscale, out bf16.
// m97 structure: 128x128 tile, BK=64, global_load_lds width=16, linear LDS.
// (r13 showed BN=64 regresses: per-wave tile amortizes the 2-barrier drain.)
// OMODE 1: out[b,h,s,d];  OMODE 2: out[b,h,d,s] transposed V, masked rows 0.
// ---------------------------------------------------------------------------
template<int OMODE>
__global__ __launch_bounds__(256)
void proj_gemm97(const bf16_t* __restrict__ A, const bf16_t* __restrict__ W,
                 const float* __restrict__ bias, bf16_t* __restrict__ Out,
                 float oscale, const int* __restrict__ mask)
{
  __shared__ __align__(16) bf16_t As[128 * 64];
  __shared__ __align__(16) bf16_t Bs[128 * 64];
  const int tid  = threadIdx.x;
  const int lane = tid & 63;
  const int w    = tid >> 6;
  const int g = lane >> 4, c = lane & 15;
  const int mq = (w >> 1) * 64, nq = (w & 1) * 64;
  const int bm = blockIdx.y, bn = blockIdx.x;

  const int rsub = lane >> 3;
  const int kc8  = (lane & 7) * 8;

  f32x4 acc[4][4] = {};

  for (int kt = 0; kt < 1024; kt += 64) {
    #pragma unroll
    for (int i = 0; i < 4; ++i) {
      const int inst = w * 4 + i;
      const int row  = inst * 8 + rsub;
      gload_lds16(A + (size_t)(bm*128 + row)*1024 + kt + kc8, &As[inst*512]);
      gload_lds16(W + (size_t)(bn*128 + row)*1024 + kt + kc8, &Bs[inst*512]);
    }
    __syncthreads();
    #pragma unroll
    for (int kk = 0; kk < 64; kk += 32) {
      bf16x8 af[4], bfv[4];
      #pragma unroll
      for (int i = 0; i < 4; ++i) {
        af[i]  = *(const bf16x8*)&As[(mq + i*16 + c)*64 + kk + 8*g];
        bfv[i] = *(const bf16x8*)&Bs[(nq + i*16 + c)*64 + kk + 8*g];
      }
      #pragma unroll
      for (int mi = 0; mi < 4; ++mi)
        #pragma unroll
        for (int ni = 0; ni < 4; ++ni)
          acc[mi][ni] = mfma16(af[mi], bfv[ni], acc[mi][ni]);
    }
    __syncthreads();
  }

  #pragma unroll
  for (int ni = 0; ni < 4; ++ni) {
    const int n = bn*128 + nq + ni*16 + c;
    const float bv = bias[n];
    const int h = n >> 6, d = n & 63;
    #pragma unroll
    for (int mi = 0; mi < 4; ++mi) {
      #pragma unroll
      for (int r = 0; r < 4; ++r) {
        const int m = bm*128 + mq + mi*16 + 4*g + r;
        const int bb = m >> 11, s = m & 2047;
        float v = (acc[mi][ni][r] + bv) * oscale;
        if (OMODE == 1) {
          Out[(((size_t)(bb*16 + h))*2048 + s)*64 + d] = (bf16_t)v;
        } else {
          if (mask[bb*2048 + s] == 0) v = 0.0f;   // fold key-mask into V rows
          Out[(((size_t)(bb*16 + h))*64 + d)*2048 + s] = (bf16_t)v;
        }
      }
    }
  }
}

// ---------------------------------------------------------------------------
// out_gemm97: split-precision GEMM from pure-bf16 inputs:
//   Out = Ah Bh + Al Bh + Ah Bl + bias   (f32-class accuracy)
// ---------------------------------------------------------------------------
__global__ __launch_bounds__(256)
void out_gemm97(const bf16_t* __restrict__ Ahg, const bf16_t* __restrict__ Alg,
                const bf16_t* __restrict__ Bhg, const bf16_t* __restrict__ Blg,
                const float* __restrict__ bias, float* __restrict__ Out)
{
  __shared__ __align__(16) bf16_t Ahs[128 * 64];
  __shared__ __align__(16) bf16_t Als[128 * 64];
  __shared__ __align__(16) bf16_t Bhs[128 * 64];
  __shared__ __align__(16) bf16_t Bls[128 * 64];
  const int tid  = threadIdx.x;
  const int lane = tid & 63;
  const int w    = tid >> 6;
  const int g = lane >> 4, c = lane & 15;
  const int mq = (w >> 1) * 64, nq = (w & 1) * 64;
  const int bm = blockIdx.y, bn = blockIdx.x;

  const int rsub = lane >> 3;
  const int kc8  = (lane & 7) * 8;

  f32x4 acc[4][4] = {};

  for (int kt = 0; kt < 1024; kt += 64) {
    #pragma unroll
    for (int i = 0; i < 4; ++i) {
      const int inst = w * 4 + i;
      const int row  = inst * 8 + rsub;
      const size_t ga = (size_t)(bm*128 + row)*1024 + kt + kc8;
      const size_t gb = (size_t)(bn*128 + row)*1024 + kt + kc8;
      gload_lds16(Ahg + ga, &Ahs[inst*512]);
      gload_lds16(Alg + ga, &Als[inst*512]);
      gload_lds16(Bhg + gb, &Bhs[inst*512]);
      gload_lds16(Blg + gb, &Bls[inst*512]);
    }
    __syncthreads();
    #pragma unroll
    for (int kk = 0; kk < 64; kk += 32) {
      bf16x8 afh[4], afl[4], bfh[4], bfl[4];
      #pragma unroll
      for (int i = 0; i < 4; ++i) {
        const int ar = (mq + i*16 + c)*64 + kk + 8*g;
        const int br = (nq + i*16 + c)*64 + kk + 8*g;
        afh[i] = *(const bf16x8*)&Ahs[ar];
        afl[i] = *(const bf16x8*)&Als[ar];
        bfh[i] = *(const bf16x8*)&Bhs[br];
        bfl[i] = *(const bf16x8*)&Bls[br];
      }
      #pragma unroll
      for (int mi = 0; mi < 4; ++mi)
        #pragma unroll
        for (int ni = 0; ni < 4; ++ni) {
          acc[mi][ni] = mfma16(afh[mi], bfh[ni], acc[mi][ni]);
          acc[mi][ni] = mfma16(afl[mi], bfh[ni], acc[mi][ni]);
          acc[mi][ni] = mfma16(afh[mi], bfl[ni], acc[mi][ni]);
        }
    }
    __syncthreads();
  }

  #pragma unroll
  for (int ni = 0; ni < 4; ++ni) {
    const int n = bn*128 + nq + ni*16 + c;
    const float bv = bias[n];
    #pragma unroll
    for (int mi = 0; mi < 4; ++mi)
      #pragma unroll
      for (int r = 0; r < 4; ++r) {
        const int m = bm*128 + mq + mi*16 + 4*g + r;
        Out[(size_t)m*1024 + n] = acc[mi][ni][r] + bv;
      }
  }
}

// ---------------------------------------------------------------------------
// Flash attention: swapped-QK^T 32x32 MFMA, in-register softmax.
//  * Chunk-serial inner loop; K/V reg->LDS double-buffer (pitch 72, 0 confl).
//  * mb loads hoisted BEFORE exp/pack; L2 latency hides under SMPK's VALU.
//  * Denominator on MFMA pipe (Ol = P~ @ maskbit); mask folded into V rows.
// Grid: 1024 (XCD-chunked). 4 waves/block, wave = 32 q-rows x full D=64.
// ---------------------------------------------------------------------------
__global__ __launch_bounds__(256, 3)
void attn_kernel(const bf16_t* __restrict__ Q, const bf16_t* __restrict__ K,
                 const bf16_t* __restrict__ Vt, const bf16_t* __restrict__ maskbit,
                 const float* __restrict__ rel_emb,
                 bf16_t* __restrict__ Ch, bf16_t* __restrict__ Cl)
{
  __shared__ float relc[257];                      // rel_emb[.,h] * log2e
  __shared__ __align__(16) bf16_t Ks[2][64][72];   // [buf][s'][d]
  __shared__ __align__(16) bf16_t Vs[2][64][72];   // [buf][d][s']

  const int tid  = threadIdx.x;
  const int w    = tid >> 6;
  const int lane = tid & 63;
  const int lq   = lane & 31;
  const int hi   = lane >> 5;

  const int bid = blockIdx.x;
  const int n   = (bid & 7) * 128 + (bid >> 3);   // XCD-chunked (1024 % 8 == 0)
  const int bh  = n >> 4;
  const int qblk= n & 15;
  const int b = bh >> 4, h = bh & 15;
  const int qw = qblk * 128 + w * 32;             // wave's q-base

  const bf16_t* Qb = Q  + ((size_t)bh * 2048) * 64;
  const bf16_t* Kb = K  + ((size_t)bh * 2048) * 64;
  const bf16_t* Vb = Vt + ((size_t)bh * 64) * 2048;
  const bf16_t* Mb = maskbit + (size_t)b * 2048;

  const int sr  = tid >> 2;            // staging row 0..63
  const int so  = (tid & 3) * 16;      // staging col

  for (int i = tid; i < 257; i += 256) relc[i] = rel_emb[i * 16 + h] * L2E;

  // ---- prologue: stage tile 0 into buf 0 ----
  {
    const bf16_t* kp = Kb + (size_t)sr * 64 + so;
    const bf16_t* vp = Vb + (size_t)sr * 2048 + so;
    i32x4 k0 = *(const i32x4*)kp, k1 = *(const i32x4*)(kp + 8);
    i32x4 v0 = *(const i32x4*)vp, v1 = *(const i32x4*)(vp + 8);
    *(i32x4*)&Ks[0][sr][so] = k0;  *(i32x4*)&Ks[0][sr][so + 8] = k1;
    *(i32x4*)&Vs[0][sr][so] = v0;  *(i32x4*)&Vs[0][sr][so + 8] = v1;
  }
  __syncthreads();

  bf16x8 qf[4];
  #pragma unroll
  for (int dc = 0; dc < 4; ++dc)
    qf[dc] = *(const bf16x8*)&Qb[(size_t)(qw + lq) * 64 + dc * 16 + 8 * hi];

  const float biasLo = relc[0];
  const float biasHi = relc[256];

  f32x16 O0 = {}, O1 = {}, Ol = {};

  // fused softmax+pack: sa (C[k][q]) -> two PV A-frags
  auto SMPK = [&](const f32x16& sa, int kvc, bf16x8& pa0, bf16x8& pa1) {
    unsigned u[8];
    const int d0 = kvc - qw;
    if (d0 >= 160 || d0 <= -160) {
      const float cb = (d0 >= 160) ? biasHi : biasLo;
      #pragma unroll
      for (int j = 0; j < 8; ++j)
        u[j] = cvtpk(exp2f(sa[2*j] + cb), exp2f(sa[2*j + 1] + cb));
    } else {
      #pragma unroll
      for (int j = 0; j < 8; ++j) {
        const int r0 = 2*j, r1 = 2*j + 1;
        const int k0r = (r0 & 3) + 8 * (r0 >> 2) + 4 * hi;
        const int k1r = (r1 & 3) + 8 * (r1 >> 2) + 4 * hi;
        int rr0 = kvc + k0r - (qw + lq);
        int rr1 = kvc + k1r - (qw + lq);
        rr0 = rr0 < -128 ? -128 : (rr0 > 128 ? 128 : rr0);
        rr1 = rr1 < -128 ? -128 : (rr1 > 128 ? 128 : rr1);
        u[j] = cvtpk(exp2f(sa[r0] + relc[rr0 + 128]),
                     exp2f(sa[r1] + relc[rr1 + 128]));
      }
    }
    asm volatile("v_permlane32_swap_b32 %0, %1" : "+v"(u[0]), "+v"(u[2]));
    asm volatile("v_permlane32_swap_b32 %0, %1" : "+v"(u[1]), "+v"(u[3]));
    i32x4 pw0 = { (int)u[0], (int)u[1], (int)u[2], (int)u[3] };
    pa0 = __builtin_bit_cast(bf16x8, pw0);
    asm volatile("v_permlane32_swap_b32 %0, %1" : "+v"(u[4]), "+v"(u[6]));
    asm volatile("v_permlane32_swap_b32 %0, %1" : "+v"(u[5]), "+v"(u[7]));
    i32x4 pw1 = { (int)u[4], (int)u[5], (int)u[6], (int)u[7] };
    pa1 = __builtin_bit_cast(bf16x8, pw1);
  };

  // one 32-row chunk end-to-end: QK^T -> (mb loads) -> exp/pack -> PV
  auto CHUNK = [&](int cur, int koff, int kvc) {
    bf16x8 kf[4];
    #pragma unroll
    for (int dc = 0; dc < 4; ++dc)
      kf[dc] = *(const bf16x8*)&Ks[cur][koff + lq][dc * 16 + 8 * hi];
    f32x16 sa = {};
    __builtin_amdgcn_s_setprio(1);
    #pragma unroll
    for (int dc = 0; dc < 4; ++dc) sa = mfma32(kf[dc], qf[dc], sa);
    __builtin_amdgcn_s_setprio(0);

    // mb loads BEFORE exp/pack: L2 latency hides under SMPK's VALU
    bf16x8 mba = *(const bf16x8*)&Mb[kvc + 8 * hi];
    bf16x8 mbb = *(const bf16x8*)&Mb[kvc + 16 + 8 * hi];

    bf16x8 pa0, pa1;
    SMPK(sa, kvc, pa0, pa1);

    const int c0 = koff;                 // 0 or 32 -> V col pairs 0/16, 32/48
    bf16x8 vf00 = *(const bf16x8*)&Vs[cur][lq]     [c0 + 8 * hi];
    bf16x8 vf01 = *(const bf16x8*)&Vs[cur][32 + lq][c0 + 8 * hi];
    bf16x8 vf10 = *(const bf16x8*)&Vs[cur][lq]     [c0 + 16 + 8 * hi];
    bf16x8 vf11 = *(const bf16x8*)&Vs[cur][32 + lq][c0 + 16 + 8 * hi];

    __builtin_amdgcn_s_setprio(1);
    O0 = mfma32(pa0, vf00, O0);
    O1 = mfma32(pa0, vf01, O1);
    Ol = mfma32(pa0, mba,  Ol);
    O0 = mfma32(pa1, vf10, O0);
    O1 = mfma32(pa1, vf11, O1);
    Ol = mfma32(pa1, mbb,  Ol);
    __builtin_amdgcn_s_setprio(0);
  };

  for (int t = 0; t < 32; ++t) {
    const int kv  = t * 64;
    const int cur = t & 1, nxt = cur ^ 1;
    const bool more = (t + 1 < 32);

    // ---- issue stage loads for tile t+1 ----
    i32x4 k0, k1, v0, v1;
    if (more) {
      const bf16_t* kp = Kb + (size_t)(kv + 64 + sr) * 64 + so;
      const bf16_t* vp = Vb + (size_t)sr * 2048 + (kv + 64) + so;
      k0 = *(const i32x4*)kp;  k1 = *(const i32x4*)(kp + 8);
      v0 = *(const i32x4*)vp;  v1 = *(const i32x4*)(vp + 8);
    }

    // ---- chunk 0 end-to-end (hides stage-load latency) ----
    CHUNK(cur, 0, kv);

    // ---- mid-iteration stage write: nxt buffer was last read in iter t-1
    //      (barrier passed); frees staging regs before chunk 1 ----
    if (more) {
      *(i32x4*)&Ks[nxt][sr][so] = k0;  *(i32x4*)&Ks[nxt][sr][so + 8] = k1;
      *(i32x4*)&Vs[nxt][sr][so] = v0;  *(i32x4*)&Vs[nxt][sr][so + 8] = v1;
    }

    // ---- chunk 1 end-to-end ----
    CHUNK(cur, 32, kv + 32);

    __syncthreads();
  }

  // ---- epilogue: each lane's Ol[reg] is its q-row's full denominator ----
  #pragma unroll
  for (int reg = 0; reg < 16; ++reg) {
    const int qrow = (reg & 3) + 8 * (reg >> 2) + 4 * hi;
    const float sum = Ol[reg];
    const float iv = (sum > 0.0f) ? 1.0f / sum : 0.0f;  // all-masked row -> 0
    const int s = qw + qrow;
    const size_t base = ((size_t)(b * 2048 + s)) * 1024 + h * 64 + lq;
    const float o0 = O0[reg] * iv, o1 = O1[reg] * iv;
    const bf16_t h0 = (bf16_t)o0, h1 = (bf16_t)o1;
    Ch[base]      = h0;  Cl[base]      = (bf16_t)(o0 - (float)h0);
    Ch[base + 32] = h1;  Cl[base + 32] = (bf16_t)(o1 - (float)h1);
  }
}

// ---------------------------------------------------------------------------
extern "C" void kernel_launch(void* const* d_in, const int* in_sizes, int n_in,
                              void* d_out, int out_size, void* d_ws, size_t ws_size,
                              hipStream_t stream)
{
  const float* q    = (const float*)d_in[0];
  const float* k    = (const float*)d_in[1];
  const float* v    = (const float*)d_in[2];
  const int*   mask = (const int*)  d_in[3];
  const float* Wq   = (const float*)d_in[4];
  const float* bq   = (const float*)d_in[5];
  const float* Wk   = (const float*)d_in[6];
  const float* bk   = (const float*)d_in[7];
  const float* Wv   = (const float*)d_in[8];
  const float* bv   = (const float*)d_in[9];
  const float* Wo   = (const float*)d_in[10];
  const float* bo   = (const float*)d_in[11];
  const float* rel  = (const float*)d_in[12];

  char* wsb = (char*)d_ws;
  bf16_t* Qw  = (bf16_t*)(wsb);                         // 16 MiB proj-Q out
  bf16_t* Kw  = (bf16_t*)(wsb + ((size_t) 16 << 20));   // 16 MiB proj-K out
  bf16_t* Vw  = (bf16_t*)(wsb + ((size_t) 32 << 20));   // 16 MiB proj-V out (T, masked)
  bf16_t* Qc  = (bf16_t*)(wsb + ((size_t) 48 << 20));   // query bf16 / later Ch
  bf16_t* Kc  = (bf16_t*)(wsb + ((size_t) 64 << 20));   // key   bf16 / later Cl
  bf16_t* Vc  = (bf16_t*)(wsb + ((size_t) 80 << 20));   // value bf16
  bf16_t* Wqc = (bf16_t*)(wsb + ((size_t) 96 << 20));   // 2 MiB each
  bf16_t* Wkc = (bf16_t*)(wsb + ((size_t) 98 << 20));
  bf16_t* Wvc = (bf16_t*)(wsb + ((size_t)100 << 20));
  bf16_t* Woh = (bf16_t*)(wsb + ((size_t)102 << 20));
  bf16_t* Wol = (bf16_t*)(wsb + ((size_t)104 << 20));
  bf16_t* Mbit= (bf16_t*)(wsb + ((size_t)106 << 20));   // 16 KiB maskbit bf16
  bf16_t* Chp = Qc;   // ctx split-high, aliases consumed Qc
  bf16_t* Clp = Kc;   // ctx split-low,  aliases consumed Kc

  const int n8t = 8192 * 1024 / 8;
  const int n8w = 1024 * 1024 / 8;
  dim3 bb(256);

  cvt_qkv<<<dim3(4096, 3), bb, 0, stream>>>(q, k, v, Qc, Kc, Vc, n8t);
  cvt_w<<<dim3(512, 5), bb, 0, stream>>>(Wq, Wk, Wv, Wo, mask,
                                         Wqc, Wkc, Wvc, Woh, Wol, Mbit, n8w);

  proj_gemm97<1><<<dim3(8, 64), bb, 0, stream>>>(Qc, Wqc, bq, Qw, QSCALE, mask);
  proj_gemm97<1><<<dim3(8, 64), bb, 0, stream>>>(Kc, Wkc, bk, Kw, 1.0f, mask);
  proj_gemm97<2><<<dim3(8, 64), bb, 0, stream>>>(Vc, Wvc, bv, Vw, 1.0f, mask);
  attn_kernel<<<dim3(1024), bb, 0, stream>>>(Qw, Kw, Vw, Mbit, rel, Chp, Clp);
  out_gemm97<<<dim3(8, 64), bb, 0, stream>>>(Chp, Clp, Woh, Wol, bo, (float*)d_out);
}